// Round 1
// baseline (338.459 us; speedup 1.0000x reference)
//
#include <hip/hip_runtime.h>

#define N_NODES 50000
#define E_EDGES 800000
#define DIN 128
#define DOUT 64

// ---------------- K1: fused L2norm + BN(eval) + Linear -> X [N,64] ----------
// block = 256 (4 waves), wave per row, grid-stride with uniform iteration
// count so __syncthreads is legal. W column j lives in 128 VGPRs of lane j.
__global__ __launch_bounds__(256) void k_x(
    const float* __restrict__ H, const float* __restrict__ gamma,
    const float* __restrict__ beta, const float* __restrict__ mean,
    const float* __restrict__ var, const float* __restrict__ W,
    const float* __restrict__ bias, float* __restrict__ X, int iters)
{
    __shared__ float s_hb[4][DIN];
    const int lane = threadIdx.x & 63;
    const int wv   = threadIdx.x >> 6;

    float w[DIN];
#pragma unroll
    for (int k = 0; k < DIN; ++k) w[k] = W[k * DOUT + lane];
    const float bj = bias[lane];

    const int k0 = lane * 2;
    const float2 g  = *(const float2*)(gamma + k0);
    const float2 be = *(const float2*)(beta  + k0);
    const float2 mn = *(const float2*)(mean  + k0);
    const float2 vr = *(const float2*)(var   + k0);
    const float sc0 = g.x / sqrtf(vr.x + 1e-5f);
    const float sc1 = g.y / sqrtf(vr.y + 1e-5f);
    const float sh0 = be.x - mn.x * sc0;
    const float sh1 = be.y - mn.y * sc1;

    for (int it = 0; it < iters; ++it) {
        const int row = (it * gridDim.x + blockIdx.x) * 4 + wv;
        const bool act = row < N_NODES;
        float2 h = make_float2(0.f, 0.f);
        if (act) h = *(const float2*)(H + (size_t)row * DIN + k0);

        float ss = h.x * h.x + h.y * h.y;
#pragma unroll
        for (int o = 32; o > 0; o >>= 1) ss += __shfl_xor(ss, o, 64);
        const float inv = 1.0f / fmaxf(sqrtf(ss), 1e-12f);

        s_hb[wv][k0]     = h.x * inv * sc0 + sh0;
        s_hb[wv][k0 + 1] = h.y * inv * sc1 + sh1;
        __syncthreads();   // orders own-wave LDS writes before reads (uniform)

        float a0 = bj, a1 = 0.f;
#pragma unroll
        for (int k = 0; k < DIN; k += 4) {
            const float4 hb = *(const float4*)&s_hb[wv][k];  // broadcast read
            a0 = fmaf(hb.x, w[k],     a0);
            a1 = fmaf(hb.y, w[k + 1], a1);
            a0 = fmaf(hb.z, w[k + 2], a0);
            a1 = fmaf(hb.w, w[k + 3], a1);
        }
        if (act) X[(size_t)row * DOUT + lane] = a0 + a1;
        __syncthreads();   // wave re-writes only its own slice next iter; this
                           // keeps barrier counts uniform across the block
    }
}

// ---------------- K2: per-row edge counts (int atomics) ---------------------
__global__ void k_count(const int* __restrict__ rows, int* __restrict__ cnt)
{
    const int e = blockIdx.x * blockDim.x + threadIdx.x;
    if (e < E_EDGES) atomicAdd(&cnt[rows[e]], 1);
}

// ---------------- K3: exclusive scan of counts (single block, 1024 thr) -----
__global__ __launch_bounds__(1024) void k_scan(
    const int* __restrict__ cnt, int* __restrict__ start, int* __restrict__ cursor)
{
    const int ITEMS = 49;                       // 1024*49 = 50176 >= 50000
    const int t = threadIdx.x;
    const int base = t * ITEMS;
    int pref[ITEMS];
    int s = 0;
#pragma unroll
    for (int i = 0; i < ITEMS; ++i) {
        const int idx = base + i;
        const int c = (idx < N_NODES) ? cnt[idx] : 0;
        pref[i] = s;
        s += c;
    }
    const int lane = t & 63, wv = t >> 6;
    int x = s;
#pragma unroll
    for (int o = 1; o < 64; o <<= 1) {
        const int y = __shfl_up(x, o, 64);
        if (lane >= o) x += y;
    }
    __shared__ int wsum[16];
    if (lane == 63) wsum[wv] = x;
    __syncthreads();
    int pre = 0;
    for (int wI = 0; wI < 16; ++wI)
        if (wI < wv) pre += wsum[wI];
    const int ex = pre + x - s;                 // exclusive prefix for thread
#pragma unroll
    for (int i = 0; i < ITEMS; ++i) {
        const int idx = base + i;
        if (idx < N_NODES) {
            const int v = ex + pref[i];
            start[idx] = v;
            cursor[idx] = v;
        }
    }
    if (t == 1023) start[N_NODES] = ex + s;     // == E
}

// ---------------- K4: scatter edges into CSR order as (val, col) pairs ------
__global__ void k_scatter(const int* __restrict__ rows, const int* __restrict__ cols,
                          const float* __restrict__ vals, int* __restrict__ cursor,
                          uint2* __restrict__ ev)
{
    const int e = blockIdx.x * blockDim.x + threadIdx.x;
    if (e < E_EDGES) {
        const int r = rows[e];
        const int pos = atomicAdd(&cursor[r], 1);
        ev[pos] = make_uint2(__float_as_uint(vals[e]), (unsigned)cols[e]);
    }
}

// ---------------- K5: row-centric SpMM + LeakyReLU --------------------------
// wave per row, lane = output column. Edge (val,col) pairs loaded coalesced
// by the wave, broadcast via shuffles; X row loads are 256B coalesced.
__global__ __launch_bounds__(256) void k_spmm(
    const int* __restrict__ start, const uint2* __restrict__ ev,
    const float* __restrict__ X, float* __restrict__ out)
{
    const int lane = threadIdx.x & 63;
    const int row  = blockIdx.x * 4 + (threadIdx.x >> 6);
    if (row >= N_NODES) return;
    const int s  = start[row];
    const int e2 = start[row + 1];
    float acc = 0.f;
    for (int c = s; c < e2; c += 64) {
        const int idx = c + lane;
        uint2 p = make_uint2(0u, 0u);
        if (idx < e2) p = ev[idx];
        const int cnt = min(e2 - c, 64);
        for (int j = 0; j < cnt; ++j) {
            const float v  = __uint_as_float(__shfl((int)p.x, j, 64));
            const int col  = __shfl((int)p.y, j, 64);
            acc = fmaf(v, X[(size_t)col * DOUT + lane], acc);
        }
    }
    out[(size_t)row * DOUT + lane] = (acc >= 0.f) ? acc : 0.01f * acc;
}

extern "C" void kernel_launch(void* const* d_in, const int* in_sizes, int n_in,
                              void* d_out, int out_size, void* d_ws, size_t ws_size,
                              hipStream_t stream)
{
    const float* H     = (const float*)d_in[0];
    const int*   rows  = (const int*)  d_in[1];
    const int*   cols  = (const int*)  d_in[2];
    const float* vals  = (const float*)d_in[3];
    const float* gamma = (const float*)d_in[4];
    const float* beta  = (const float*)d_in[5];
    const float* mean  = (const float*)d_in[6];
    const float* var   = (const float*)d_in[7];
    const float* W     = (const float*)d_in[8];
    const float* bias  = (const float*)d_in[9];
    float* out = (float*)d_out;

    char* ws = (char*)d_ws;
    float* X      = (float*)(ws);                         // 12,800,000 B
    int*   cnt    = (int*)  (ws + 12800000);              //    200,000 B
    int*   startp = (int*)  (ws + 13000000);              //    200,004 B
    int*   cursor = (int*)  (ws + 13200016);              //    200,000 B
    uint2* ev     = (uint2*)(ws + 13400016);              //  6,400,000 B

    hipMemsetAsync(cnt, 0, N_NODES * sizeof(int), stream);

    const int gridx = 1024;
    const int iters = (N_NODES + gridx * 4 - 1) / (gridx * 4);
    k_x<<<gridx, 256, 0, stream>>>(H, gamma, beta, mean, var, W, bias, X, iters);
    k_count<<<(E_EDGES + 255) / 256, 256, 0, stream>>>(rows, cnt);
    k_scan<<<1, 1024, 0, stream>>>(cnt, startp, cursor);
    k_scatter<<<(E_EDGES + 255) / 256, 256, 0, stream>>>(rows, cols, vals, cursor, ev);
    k_spmm<<<(N_NODES + 3) / 4, 256, 0, stream>>>(startp, ev, X, out);
}

// Round 2
// 241.915 us; speedup vs baseline: 1.3991x; 1.3991x over previous
//
#include <hip/hip_runtime.h>

#define N_NODES 50000
#define E_EDGES 800000
#define DIN 128
#define DOUT 64
#define SCAN_BLOCKS 49   // 49 * 1024 = 50176 >= N_NODES

// ---------------- K1: fused L2norm + BN(eval) + Linear -> X [N,64] ----------
__global__ __launch_bounds__(256) void k_x(
    const float* __restrict__ H, const float* __restrict__ gamma,
    const float* __restrict__ beta, const float* __restrict__ mean,
    const float* __restrict__ var, const float* __restrict__ W,
    const float* __restrict__ bias, float* __restrict__ X, int iters)
{
    __shared__ float s_hb[4][DIN];
    const int lane = threadIdx.x & 63;
    const int wv   = threadIdx.x >> 6;

    float w[DIN];
#pragma unroll
    for (int k = 0; k < DIN; ++k) w[k] = W[k * DOUT + lane];
    const float bj = bias[lane];

    const int k0 = lane * 2;
    const float2 g  = *(const float2*)(gamma + k0);
    const float2 be = *(const float2*)(beta  + k0);
    const float2 mn = *(const float2*)(mean  + k0);
    const float2 vr = *(const float2*)(var   + k0);
    const float sc0 = g.x / sqrtf(vr.x + 1e-5f);
    const float sc1 = g.y / sqrtf(vr.y + 1e-5f);
    const float sh0 = be.x - mn.x * sc0;
    const float sh1 = be.y - mn.y * sc1;

    for (int it = 0; it < iters; ++it) {
        const int row = (it * gridDim.x + blockIdx.x) * 4 + wv;
        const bool act = row < N_NODES;
        float2 h = make_float2(0.f, 0.f);
        if (act) h = *(const float2*)(H + (size_t)row * DIN + k0);

        float ss = h.x * h.x + h.y * h.y;
#pragma unroll
        for (int o = 32; o > 0; o >>= 1) ss += __shfl_xor(ss, o, 64);
        const float inv = 1.0f / fmaxf(sqrtf(ss), 1e-12f);

        s_hb[wv][k0]     = h.x * inv * sc0 + sh0;
        s_hb[wv][k0 + 1] = h.y * inv * sc1 + sh1;
        __syncthreads();

        float a0 = bj, a1 = 0.f;
#pragma unroll
        for (int k = 0; k < DIN; k += 4) {
            const float4 hb = *(const float4*)&s_hb[wv][k];
            a0 = fmaf(hb.x, w[k],     a0);
            a1 = fmaf(hb.y, w[k + 1], a1);
            a0 = fmaf(hb.z, w[k + 2], a0);
            a1 = fmaf(hb.w, w[k + 3], a1);
        }
        if (act) X[(size_t)row * DOUT + lane] = a0 + a1;
        __syncthreads();
    }
}

// ---------------- K2: per-row edge counts (int atomics) ---------------------
__global__ void k_count(const int* __restrict__ rows, int* __restrict__ cnt)
{
    const int e = blockIdx.x * blockDim.x + threadIdx.x;
    if (e < E_EDGES) atomicAdd(&cnt[rows[e]], 1);
}

// ---------------- K3a: block-level exclusive scan (1024 elems / block) ------
__global__ __launch_bounds__(256) void k_scan1(
    const int* __restrict__ cnt, int* __restrict__ start, int* __restrict__ bsum)
{
    const int b = blockIdx.x, t = threadIdx.x;
    const int base = b * 1024 + t * 4;
    int c0 = 0, c1 = 0, c2 = 0, c3 = 0;
    if (base + 3 < N_NODES) {
        const int4 c = *(const int4*)(cnt + base);
        c0 = c.x; c1 = c.y; c2 = c.z; c3 = c.w;
    } else {
        if (base     < N_NODES) c0 = cnt[base];
        if (base + 1 < N_NODES) c1 = cnt[base + 1];
        if (base + 2 < N_NODES) c2 = cnt[base + 2];
        if (base + 3 < N_NODES) c3 = cnt[base + 3];
    }
    const int s = c0 + c1 + c2 + c3;
    const int lane = t & 63, wv = t >> 6;
    int x = s;
#pragma unroll
    for (int o = 1; o < 64; o <<= 1) {
        const int y = __shfl_up(x, o, 64);
        if (lane >= o) x += y;
    }
    __shared__ int wsum[4];
    if (lane == 63) wsum[wv] = x;
    __syncthreads();
    int wpre = 0;
    for (int i = 0; i < wv; ++i) wpre += wsum[i];
    const int ex = wpre + x - s;      // exclusive prefix within block
    const int p0 = ex, p1 = ex + c0, p2 = p1 + c1, p3 = p2 + c2;
    if (base + 3 < N_NODES) {
        *(int4*)(start + base) = make_int4(p0, p1, p2, p3);
    } else {
        if (base     < N_NODES) start[base]     = p0;
        if (base + 1 < N_NODES) start[base + 1] = p1;
        if (base + 2 < N_NODES) start[base + 2] = p2;
        if (base + 3 < N_NODES) start[base + 3] = p3;
    }
    if (t == 255) bsum[b] = ex + s;   // block total
}

// ---------------- K3b: 1-wave scan of the 49 block sums ---------------------
__global__ void k_scan2(const int* __restrict__ bsum, int* __restrict__ boff,
                        int* __restrict__ startN)
{
    const int lane = threadIdx.x;
    const int v = (lane < SCAN_BLOCKS) ? bsum[lane] : 0;
    int x = v;
#pragma unroll
    for (int o = 1; o < 64; o <<= 1) {
        const int y = __shfl_up(x, o, 64);
        if (lane >= o) x += y;
    }
    if (lane < SCAN_BLOCKS) boff[lane] = x - v;
    if (lane == 63) startN[0] = x;    // total == E
}

// ---------------- K3c: apply block offsets, init cursor ---------------------
__global__ __launch_bounds__(256) void k_scan3(
    int* __restrict__ start, const int* __restrict__ boff, int* __restrict__ cursor)
{
    const int b = blockIdx.x, t = threadIdx.x;
    const int base = b * 1024 + t * 4;
    const int off = boff[b];
    if (base + 3 < N_NODES) {
        int4 p = *(const int4*)(start + base);
        p.x += off; p.y += off; p.z += off; p.w += off;
        *(int4*)(start + base) = p;
        *(int4*)(cursor + base) = p;
    } else {
        for (int i = 0; i < 4; ++i)
            if (base + i < N_NODES) {
                const int v = start[base + i] + off;
                start[base + i] = v;
                cursor[base + i] = v;
            }
    }
}

// ---------------- K4: scatter edges into CSR order as (val, col) pairs ------
__global__ void k_scatter(const int* __restrict__ rows, const int* __restrict__ cols,
                          const float* __restrict__ vals, int* __restrict__ cursor,
                          uint2* __restrict__ ev)
{
    const int e = blockIdx.x * blockDim.x + threadIdx.x;
    if (e < E_EDGES) {
        const int r = rows[e];
        const int pos = atomicAdd(&cursor[r], 1);
        ev[pos] = make_uint2(__float_as_uint(vals[e]), (unsigned)cols[e]);
    }
}

// ---------------- K5: row-centric SpMM + LeakyReLU --------------------------
// wave per row, lane = output column; edge loop unrolled x4 for 4 gathers in
// flight (the gather X[col*64+lane] is the serial-latency chain otherwise).
__global__ __launch_bounds__(256) void k_spmm(
    const int* __restrict__ start, const uint2* __restrict__ ev,
    const float* __restrict__ X, float* __restrict__ out)
{
    const int lane = threadIdx.x & 63;
    const int row  = blockIdx.x * 4 + (threadIdx.x >> 6);
    if (row >= N_NODES) return;
    const int s  = start[row];
    const int e2 = start[row + 1];
    float acc = 0.f;
    for (int c = s; c < e2; c += 64) {
        const int idx = c + lane;
        uint2 p = make_uint2(0u, 0u);
        if (idx < e2) p = ev[idx];
        const int cnt = min(e2 - c, 64);
        int j = 0;
        for (; j + 3 < cnt; j += 4) {
            const float v0 = __uint_as_float(__shfl((int)p.x, j,     64));
            const int   c0 = __shfl((int)p.y, j,     64);
            const float v1 = __uint_as_float(__shfl((int)p.x, j + 1, 64));
            const int   c1 = __shfl((int)p.y, j + 1, 64);
            const float v2 = __uint_as_float(__shfl((int)p.x, j + 2, 64));
            const int   c2 = __shfl((int)p.y, j + 2, 64);
            const float v3 = __uint_as_float(__shfl((int)p.x, j + 3, 64));
            const int   c3 = __shfl((int)p.y, j + 3, 64);
            const float x0 = X[(size_t)c0 * DOUT + lane];
            const float x1 = X[(size_t)c1 * DOUT + lane];
            const float x2 = X[(size_t)c2 * DOUT + lane];
            const float x3 = X[(size_t)c3 * DOUT + lane];
            acc = fmaf(v0, x0, acc);
            acc = fmaf(v1, x1, acc);
            acc = fmaf(v2, x2, acc);
            acc = fmaf(v3, x3, acc);
        }
        for (; j < cnt; ++j) {
            const float v  = __uint_as_float(__shfl((int)p.x, j, 64));
            const int col  = __shfl((int)p.y, j, 64);
            acc = fmaf(v, X[(size_t)col * DOUT + lane], acc);
        }
    }
    out[(size_t)row * DOUT + lane] = (acc >= 0.f) ? acc : 0.01f * acc;
}

extern "C" void kernel_launch(void* const* d_in, const int* in_sizes, int n_in,
                              void* d_out, int out_size, void* d_ws, size_t ws_size,
                              hipStream_t stream)
{
    const float* H     = (const float*)d_in[0];
    const int*   rows  = (const int*)  d_in[1];
    const int*   cols  = (const int*)  d_in[2];
    const float* vals  = (const float*)d_in[3];
    const float* gamma = (const float*)d_in[4];
    const float* beta  = (const float*)d_in[5];
    const float* mean  = (const float*)d_in[6];
    const float* var   = (const float*)d_in[7];
    const float* W     = (const float*)d_in[8];
    const float* bias  = (const float*)d_in[9];
    float* out = (float*)d_out;

    char* ws = (char*)d_ws;
    float* X      = (float*)(ws);                         // 12,800,000 B
    int*   cnt    = (int*)  (ws + 12800000);              //    200,000 B
    int*   startp = (int*)  (ws + 13000000);              //    200,004 B
    int*   cursor = (int*)  (ws + 13200016);              //    200,000 B
    uint2* ev     = (uint2*)(ws + 13400016);              //  6,400,000 B
    int*   bsum   = (int*)  (ws + 19800016);              //        196 B
    int*   boff   = (int*)  (ws + 19800212);              //        196 B

    hipMemsetAsync(cnt, 0, N_NODES * sizeof(int), stream);

    const int gridx = 1024;
    const int iters = (N_NODES + gridx * 4 - 1) / (gridx * 4);
    k_x<<<gridx, 256, 0, stream>>>(H, gamma, beta, mean, var, W, bias, X, iters);
    k_count<<<(E_EDGES + 255) / 256, 256, 0, stream>>>(rows, cnt);
    k_scan1<<<SCAN_BLOCKS, 256, 0, stream>>>(cnt, startp, bsum);
    k_scan2<<<1, 64, 0, stream>>>(bsum, boff, startp + N_NODES);
    k_scan3<<<SCAN_BLOCKS, 256, 0, stream>>>(startp, boff, cursor);
    k_scatter<<<(E_EDGES + 255) / 256, 256, 0, stream>>>(rows, cols, vals, cursor, ev);
    k_spmm<<<(N_NODES + 3) / 4, 256, 0, stream>>>(startp, ev, X, out);
}